// Round 11
// baseline (524.111 us; speedup 1.0000x reference)
//
#include <hip/hip_runtime.h>

// SuperExpertMoE — round 11: persistent work-queue GEMMs (round-8 inner loop unchanged),
// tail-filling: w2 cast folded into up-GEMM queue, w1 cast folded into gate launch.
// gate+castW1 -> route(+zero ctrs) -> finalize -> up GEMM(+castW2 tail) -> down GEMM -> gather.

#define TOKS 4096
#define CD 2048
#define FD 1408
#define RROWS 8192    // exactly 2 routed slots per token
#define W14 5767168   // 8*1408*2048/4  (== 8*2048*1408/4)
#define TOTF4 6488064 // 9*1408*2048/4
#define CASTCHUNK 32768
#define NCAST2 198    // TOTF4 / CASTCHUNK exactly

typedef unsigned short u16;
typedef float f32x4 __attribute__((ext_vector_type(4)));
typedef __bf16 bf16x8 __attribute__((ext_vector_type(8)));

__device__ __forceinline__ u16 f2bf(float f) {
  unsigned u = __float_as_uint(f);
  u += 0x7fffu + ((u >> 16) & 1u);   // RNE
  return (u16)(u >> 16);
}

// ---------------- gate (blocks 0-1023) + w1/sw1 cast (all 2048 blocks) ----------------
__global__ __launch_bounds__(256) void gatecast_kernel(
    const float* __restrict__ x, const float* __restrict__ gw,
    float* __restrict__ combine, float* __restrict__ part, int* __restrict__ sel,
    u16* __restrict__ xb,
    const float4* __restrict__ w1, const float4* __restrict__ sw1, u16* __restrict__ w1b)
{
  if (blockIdx.x < 1024) {
    const int lane = threadIdx.x & 63;
    const int wave = threadIdx.x >> 6;
    const int n = blockIdx.x * 4 + wave;
    const float* xr = x + (size_t)n * CD;
    u16* xbr = xb + (size_t)n * CD;
    float p[8] = {0,0,0,0,0,0,0,0};
#pragma unroll
    for (int it = 0; it < 8; ++it) {
      const int idx = it * 256 + lane * 4;
      const float4 xv = *(const float4*)(xr + idx);
      ushort4 xo;
      xo.x = f2bf(xv.x); xo.y = f2bf(xv.y); xo.z = f2bf(xv.z); xo.w = f2bf(xv.w);
      *(ushort4*)(xbr + idx) = xo;
#pragma unroll
      for (int e = 0; e < 8; ++e) {
        const float4 gv = *(const float4*)(gw + e * CD + idx);
        p[e] += xv.x * gv.x + xv.y * gv.y + xv.z * gv.z + xv.w * gv.w;
      }
    }
#pragma unroll
    for (int e = 0; e < 8; ++e) {
#pragma unroll
      for (int m = 32; m > 0; m >>= 1) p[e] += __shfl_xor(p[e], m, 64);
    }
    float mx = p[0];
#pragma unroll
    for (int e = 1; e < 8; ++e) mx = fmaxf(mx, p[e]);
    float s = 0.f, pr[8];
#pragma unroll
    for (int e = 0; e < 8; ++e) { pr[e] = __expf(p[e] - mx); s += pr[e]; }
    const float inv = 1.f / s;
#pragma unroll
    for (int e = 0; e < 8; ++e) pr[e] *= inv;
    const float lse = mx + __logf(s);
    int i1 = 0;
#pragma unroll
    for (int e = 1; e < 8; ++e) if (pr[e] > pr[i1]) i1 = e;   // strict > : lowest-index tie-break
    int i2 = (i1 == 0) ? 1 : 0;
#pragma unroll
    for (int e = 0; e < 8; ++e) if (e != i1 && pr[e] > pr[i2]) i2 = e;
    const float rs = 1.f / (pr[i1] + pr[i2]);

    __shared__ float pl[4][12];
    if (lane == 0) {
      float* cr = combine + (size_t)n * 16;
#pragma unroll
      for (int e = 0; e < 8; ++e) cr[e] = 0.f;
      cr[i1] = pr[i1] * rs;
      cr[i2] = pr[i2] * rs;
      cr[8] = 1.0f;
      sel[n] = i1 | (i2 << 4);
#pragma unroll
      for (int e = 0; e < 8; ++e) pl[wave][e] = pr[e];
      pl[wave][8] = lse * lse;
    }
    __syncthreads();
    if (threadIdx.x < 9)
      part[(size_t)blockIdx.x * 16 + threadIdx.x] =
          pl[0][threadIdx.x] + pl[1][threadIdx.x] + pl[2][threadIdx.x] + pl[3][threadIdx.x];
  }
  // all blocks: cast w1 (8 experts) then sw1 -> w1b, grid-stride
  const int stride = gridDim.x * blockDim.x;
  for (int j = blockIdx.x * blockDim.x + threadIdx.x; j < TOTF4; j += stride) {
    const float4 v = (j < W14) ? w1[j] : sw1[j - W14];
    ushort4 o;
    o.x = f2bf(v.x); o.y = f2bf(v.y); o.z = f2bf(v.z); o.w = f2bf(v.w);
    *(ushort4*)(w1b + (size_t)j * 4) = o;
  }
}

// ---------------- routing compaction (single wave, deterministic) + 128-row tile map -----
__global__ void route_kernel(const int* __restrict__ sel, int* __restrict__ le,
                             int* __restrict__ pos, int* __restrict__ cntoff,
                             int* __restrict__ tileMap)
{
  const int lane = threadIdx.x;
  const unsigned long long lt = (1ull << lane) - 1ull;
  int cnt[8] = {0,0,0,0,0,0,0,0};
  for (int c = 0; c < TOKS / 64; ++c) {
    const int s = sel[c * 64 + lane];
    const int e1 = s & 15, e2 = (s >> 4) & 15;
#pragma unroll
    for (int e = 0; e < 8; ++e)
      cnt[e] += __popcll(__ballot(e1 == e)) + __popcll(__ballot(e2 == e));
  }
  int off[8]; off[0] = 0;
#pragma unroll
  for (int e = 1; e < 8; ++e) off[e] = off[e - 1] + cnt[e - 1];
  int base[8];
#pragma unroll
  for (int e = 0; e < 8; ++e) base[e] = off[e];
  for (int c = 0; c < TOKS / 64; ++c) {
    const int n = c * 64 + lane;
    const int s = sel[n];
    const int e1 = s & 15, e2 = (s >> 4) & 15;
#pragma unroll
    for (int e = 0; e < 8; ++e) {
      const unsigned long long m1 = __ballot(e1 == e);
      const unsigned long long m2 = __ballot(e2 == e);
      if (e1 == e) { const int r = base[e] + __popcll(m1 & lt); le[r] = n; pos[2 * n] = r; }
      if (e2 == e) { const int r = base[e] + __popcll(m1) + __popcll(m2 & lt); le[r] = n; pos[2 * n + 1] = r; }
      base[e] += __popcll(m1) + __popcll(m2);
    }
  }
  if (lane < 8) { cntoff[lane] = cnt[lane]; cntoff[16 + lane] = off[lane]; }
  if (lane == 8) { cntoff[8] = TOKS; cntoff[24] = RROWS; }
  if (lane == 9) { cntoff[26] = 0; cntoff[27] = 0; }   // work-queue counters (reset every launch)
  if (lane == 0) {
    int t = 0;
    for (int e = 0; e < 8; ++e)
      for (int m = 0; m < cnt[e]; m += 128) tileMap[t++] = e | (m << 4);
    for (int m = 0; m < TOKS; m += 128) tileMap[t++] = 8 | (m << 4);
    cntoff[25] = t;   // NT <= 104
  }
}

// deterministic tree reduce -> loss scalar
__global__ void finalize_kernel(const float* __restrict__ part, float* __restrict__ loss_out)
{
  __shared__ float sm[256][10];
  float loc[9] = {0,0,0,0,0,0,0,0,0};
  for (int b = threadIdx.x; b < 1024; b += 256)
#pragma unroll
    for (int c = 0; c < 9; ++c) loc[c] += part[(size_t)b * 16 + c];
#pragma unroll
  for (int c = 0; c < 9; ++c) sm[threadIdx.x][c] = loc[c];
  __syncthreads();
  for (int off = 128; off > 0; off >>= 1) {
    if (threadIdx.x < off)
#pragma unroll
      for (int c = 0; c < 9; ++c) sm[threadIdx.x][c] += sm[threadIdx.x + off][c];
    __syncthreads();
  }
  if (threadIdx.x == 0) {
    float aux = 0.f;
#pragma unroll
    for (int e = 0; e < 8; ++e) { const float m = sm[0][e] * (1.f / TOKS); aux += m * m; }
    const float z = sm[0][8] * (1.f / TOKS);
    loss_out[0] = 0.01f * aux + 0.001f * z;
  }
}

// ---------------- persistent-queue GEMM: 128x128, BK=64, 4 waves, round-8 inner loop -----
// MODE 0 (up):   tiles then NCAST2 w2-cast chunks from queue cntoff[26].
// MODE 1 (down): tiles from queue cntoff[27].
// LDS tile [128][64] bf16, 16B-group swizzle (pre-swizzled global src; reads apply same XOR).
template<int MODE>
__global__ __launch_bounds__(256, 2) void gemm_bt(
    const u16* __restrict__ Abase, const u16* __restrict__ Bbase,
    u16* __restrict__ outBF, const float* __restrict__ combine,
    const int* __restrict__ le, int* __restrict__ cntoff,
    const int* __restrict__ tileMap,
    const float4* __restrict__ c2a, const float4* __restrict__ c2b, u16* __restrict__ c2dst)
{
  constexpr int K   = (MODE == 0) ? CD : FD;
  constexpr int OS  = (MODE == 0) ? FD : CD;
  constexpr int NY  = (MODE == 0) ? 11 : 16;
  constexpr int NKT = K >> 6;                 // 32 / 22 (even: buf parity safe across tiles)

  __shared__ __attribute__((aligned(16))) u16 smA[2][128 * 64];  // 2 x 16 KB
  __shared__ __attribute__((aligned(16))) u16 smB[2][128 * 64];  // 2 x 16 KB -> 64 KB
  __shared__ int sh_i;

  const int tid  = threadIdx.x;
  const int ln   = tid & 63;
  const int wv   = tid >> 6;
  const int wr   = wv >> 1, wc = wv & 1;
  const int la15 = ln & 15;
  const int g16  = ln >> 4;
  const int srow = ln >> 3;                        // 0..7
  const int sgrp = (((ln & 7) ^ srow) << 3);       // pre-swizzled elem offset

#define STAGE(buf, kt)                                                                        \
  {                                                                                           \
    const int kof_ = (kt) << 6;                                                               \
    _Pragma("unroll")                                                                         \
    for (int c_ = 0; c_ < 4; ++c_) {                                                          \
      __builtin_amdgcn_global_load_lds(                                                       \
          (const __attribute__((address_space(1))) void*)(pA[c_] + kof_),                     \
          (__attribute__((address_space(3))) void*)(&smA[buf][c_ * 2048 + wv * 512]),         \
          16, 0, 0);                                                                          \
      __builtin_amdgcn_global_load_lds(                                                       \
          (const __attribute__((address_space(1))) void*)(pB[c_] + kof_),                     \
          (__attribute__((address_space(3))) void*)(&smB[buf][c_ * 2048 + wv * 512]),         \
          16, 0, 0);                                                                          \
    }                                                                                         \
  }

  for (;;) {
    __syncthreads();                       // all waves done with previous tile's LDS
    if (tid == 0) sh_i = atomicAdd(&cntoff[26 + MODE], 1);
    __syncthreads();
    const int i = sh_i;
    const int ntile = cntoff[25] * NY;
    if (i >= ntile) {
      if (MODE == 1) break;
      const int c = i - ntile;             // w2-cast tail work
      if (c >= NCAST2) break;
      const int cbase = c * CASTCHUNK;
      for (int k = tid; k < CASTCHUNK; k += 256) {
        const int j = cbase + k;
        const float4 v = (j < W14) ? c2a[j] : c2b[j - W14];
        ushort4 o;
        o.x = f2bf(v.x); o.y = f2bf(v.y); o.z = f2bf(v.z); o.w = f2bf(v.w);
        *(ushort4*)(c2dst + (size_t)j * 4) = o;
      }
      continue;
    }

    const int t = i / NY;
    const int y = i - t * NY;
    const int packed = tileMap[t];
    const int e = packed & 15;
    const int m0 = packed >> 4;
    const int cnt = cntoff[e];
    const int off = cntoff[16 + e];
    const int n0 = y * 128;
    const u16* Bp = Bbase + (size_t)e * FD * CD;

    const u16* pA[4];
    const u16* pB[4];
#pragma unroll
    for (int c = 0; c < 4; ++c) {
      const int rloc = c * 32 + wv * 8 + srow;
      size_t arow;
      if (MODE == 0)
        arow = (e == 8) ? (size_t)(m0 + rloc)
                        : (size_t)le[min(off + m0 + rloc, RROWS - 1)];
      else
        arow = (size_t)(off + m0 + rloc);
      pA[c] = Abase + arow * K + sgrp;
      pB[c] = Bp + (size_t)(n0 + rloc) * K + sgrp;
    }

    f32x4 acc[4][4] = {};

    // prologue: tile 0 staged, wait, barrier
    STAGE(0, 0)
    asm volatile("s_waitcnt vmcnt(0)" ::: "memory");
    __builtin_amdgcn_s_barrier();
    asm volatile("" ::: "memory");

#pragma unroll 1
    for (int kt = 0; kt < NKT; ++kt) {
      const int cur = kt & 1;
      if (kt + 1 < NKT) STAGE(cur ^ 1, kt + 1)     // issue next tile BEFORE compute
      const u16* sa = &smA[cur][0];
      const u16* sb = &smB[cur][0];
#pragma unroll
      for (int kk = 0; kk < 2; ++kk) {
        const int gg = kk * 4 + g16;
        bf16x8 af[4], bv[4];
#pragma unroll
        for (int ii = 0; ii < 4; ++ii) {
          const int r = wr * 64 + ii * 16 + la15;
          af[ii] = *(const bf16x8*)(sa + r * 64 + (((gg ^ (r & 7))) << 3));
        }
#pragma unroll
        for (int j = 0; j < 4; ++j) {
          const int r = wc * 64 + j * 16 + la15;
          bv[j] = *(const bf16x8*)(sb + r * 64 + (((gg ^ (r & 7))) << 3));
        }
#pragma unroll
        for (int ii = 0; ii < 4; ++ii)
#pragma unroll
          for (int j = 0; j < 4; ++j)
            acc[ii][j] = __builtin_amdgcn_mfma_f32_16x16x32_bf16(af[ii], bv[j], acc[ii][j], 0, 0, 0);
      }
      if (kt + 1 < NKT) {
        asm volatile("s_waitcnt vmcnt(0)" ::: "memory");   // next tile landed
        asm volatile("" ::: "memory");
        __builtin_amdgcn_s_barrier();                       // all waves done reading cur
        asm volatile("" ::: "memory");
      }
    }

    // epilogue — C/D layout: col = lane&15, row = (lane>>4)*4 + q
#pragma unroll
    for (int ii = 0; ii < 4; ++ii) {
      const int rloc0 = wr * 64 + ii * 16 + (g16 << 2);
#pragma unroll
      for (int q = 0; q < 4; ++q) {
        const int rloc = rloc0 + q;
        if (m0 + rloc >= cnt) continue;
        float sc = 1.f;
        if (MODE == 0) {
          const int tok = (e == 8) ? (m0 + rloc) : le[off + m0 + rloc];
          sc = combine[(size_t)tok * 16 + e];
        }
#pragma unroll
        for (int j = 0; j < 4; ++j) {
          const int col = n0 + wc * 64 + j * 16 + la15;
          const float v = acc[ii][j][q];
          const float h = (MODE == 0) ? (sc * v * (1.f / (1.f + __expf(-v)))) : v;
          outBF[(size_t)(off + m0 + rloc) * OS + col] = f2bf(h);
        }
      }
    }
  }
#undef STAGE
}

// ---------------- gather-sum: out[n] = alpha*(Yc[p1]+Yc[p2]+Yc[8192+n]) + beta*x[n] --------
__global__ __launch_bounds__(256) void gather_kernel(
    const u16* __restrict__ Yc, const int* __restrict__ pos,
    const float* __restrict__ x, const float* __restrict__ alpha,
    const float* __restrict__ beta, float* __restrict__ out)
{
  const int n = blockIdx.x;
  const int c0 = threadIdx.x * 8;
  const int p1 = pos[2 * n], p2 = pos[2 * n + 1];
  const bf16x8 a = *(const bf16x8*)(Yc + (size_t)p1 * CD + c0);
  const bf16x8 b = *(const bf16x8*)(Yc + (size_t)p2 * CD + c0);
  const bf16x8 s = *(const bf16x8*)(Yc + ((size_t)RROWS + n) * CD + c0);
  const float* xr = x + (size_t)n * CD + c0;
  float* orow = out + (size_t)n * CD + c0;
#pragma unroll
  for (int j = 0; j < 8; ++j) {
    const float v = (float)a[j] + (float)b[j] + (float)s[j];
    orow[j] = alpha[c0 + j] * v + beta[c0 + j] * xr[j];
  }
}

extern "C" void kernel_launch(void* const* d_in, const int* in_sizes, int n_in,
                              void* d_out, int out_size, void* d_ws, size_t ws_size,
                              hipStream_t stream)
{
  (void)in_sizes; (void)n_in; (void)out_size; (void)ws_size;
  const float* x     = (const float*)d_in[0];
  const float* gw    = (const float*)d_in[1];
  const float* w1    = (const float*)d_in[2];
  const float* w2    = (const float*)d_in[3];
  const float* sw1   = (const float*)d_in[4];
  const float* sw2   = (const float*)d_in[5];
  const float* alpha = (const float*)d_in[6];
  const float* beta  = (const float*)d_in[7];
  float* out = (float*)d_out;

  char* ws = (char*)d_ws;
  float* combine = (float*)(ws + 0);            // 256 KB
  float* part    = (float*)(ws + 262144);       // 64 KB
  int*   sel     = (int*)(ws + 327680);         // 16 KB
  int*   le      = (int*)(ws + 344064);         // 32 KB
  int*   pos     = (int*)(ws + 376832);         // 32 KB
  int*   cntoff  = (int*)(ws + 409600);         // 256 B (incl. queue ctrs [26],[27])
  int*   tileMap = (int*)(ws + 409856);         // 512 B
  u16*   xb      = (u16*)(ws + 410368);         // 16 MB
  u16*   w1b     = (u16*)(ws + 17187584);       // 51.9 MB (w1 x8, then sw1)
  u16*   w2b     = (u16*)(ws + 69092096);       // 51.9 MB (w2 x8, then sw2)
  u16*   Hcomp   = (u16*)(ws + 120996608);      // 12288*1408*2 = 34.6 MB
  u16*   Ycomp   = (u16*)(ws + 155599616);      // 12288*2048*2 = 50.3 MB

  gatecast_kernel<<<2048, 256, 0, stream>>>(x, gw, combine, part, sel, xb,
                                            (const float4*)w1, (const float4*)sw1, w1b);
  route_kernel<<<1, 64, 0, stream>>>(sel, le, pos, cntoff, tileMap);
  finalize_kernel<<<1, 256, 0, stream>>>(part, out + (size_t)TOKS * CD);
  gemm_bt<0><<<512, 256, 0, stream>>>(xb, w1b, Hcomp, combine, le, cntoff, tileMap,
                                      (const float4*)w2, (const float4*)sw2, w2b);
  gemm_bt<1><<<512, 256, 0, stream>>>(Hcomp, w2b, Ycomp, nullptr, le, cntoff, tileMap,
                                      nullptr, nullptr, nullptr);
  gather_kernel<<<TOKS, 256, 0, stream>>>(Ycomp, pos, x, alpha, beta, out);
}